// Round 1
// baseline (78.336 us; speedup 1.0000x reference)
//
#include <hip/hip_runtime.h>

// Pairwise dot products + scalar bias:
//   out[b,n,m] = sum_d x1[b,n,d] * x2[b,m,d] + const
// B=4, N=M=4096, D=32, fp32 in/out.
//
// Store-BW-bound kernel (268 MB out). fp32 VALU compute (no fp32 MFMA on
// CDNA4) fits under the store roofline, so no low-precision tricks needed.

constexpr int Bv = 4;
constexpr int Nv = 4096;
constexpr int Mv = 4096;
constexpr int Dv = 32;
constexpr int TILE = 64;      // output tile is TILE x TILE
constexpr int LROW = 68;      // LDS row stride in words: 68*4=272 B, 16B-aligned, breaks pow2 conflicts

__global__ __launch_bounds__(256)
void pairwise_dot_bias_kernel(const float* __restrict__ x1,
                              const float* __restrict__ x2,
                              const float* __restrict__ cbias,
                              float* __restrict__ out) {
    // d-major LDS tiles: a_s[d][row], b_s[d][col]
    __shared__ float a_s[Dv][LROW];
    __shared__ float b_s[Dv][LROW];

    const int b  = blockIdx.z;
    const int n0 = blockIdx.y * TILE;
    const int m0 = blockIdx.x * TILE;

    const int t      = threadIdx.x;   // 0..255
    const int lane_r = t & 63;        // row within tile (consecutive lanes -> consecutive rows)
    const int wq     = t >> 6;        // wave id 0..3 -> d-quad

    const float* x1b = x1 + (size_t)b * Nv * Dv;
    const float* x2b = x2 + (size_t)b * Mv * Dv;

    // ---- load phase: whole D=32 slab in one shot (two d-quads per wave) ----
    // Global: each lane reads one float4 (16 B) per pass; input region is tiny
    // and L2-resident. LDS writes: lanes 0..63 hit rows 0..63 at fixed d ->
    // banks = (4d + r) % 32 with r spanning 0..63 -> <=2-way (free).
    #pragma unroll
    for (int p = 0; p < 2; ++p) {
        const int dq = wq + p * 4;    // 0..7
        const float4 av = *reinterpret_cast<const float4*>(
            x1b + (size_t)(n0 + lane_r) * Dv + dq * 4);
        const float4 bv = *reinterpret_cast<const float4*>(
            x2b + (size_t)(m0 + lane_r) * Dv + dq * 4);
        a_s[dq * 4 + 0][lane_r] = av.x;
        a_s[dq * 4 + 1][lane_r] = av.y;
        a_s[dq * 4 + 2][lane_r] = av.z;
        a_s[dq * 4 + 3][lane_r] = av.w;
        b_s[dq * 4 + 0][lane_r] = bv.x;
        b_s[dq * 4 + 1][lane_r] = bv.y;
        b_s[dq * 4 + 2][lane_r] = bv.z;
        b_s[dq * 4 + 3][lane_r] = bv.w;
    }
    __syncthreads();

    // ---- compute phase: 4x4 micro-tile per thread ----
    const int tx = t & 15;            // col group: cols m0 + 4*tx .. +3
    const int ty = t >> 4;            // row group: rows n0 + 4*ty .. +3

    float acc[4][4];
    #pragma unroll
    for (int i = 0; i < 4; ++i)
        #pragma unroll
        for (int j = 0; j < 4; ++j)
            acc[i][j] = 0.0f;

    #pragma unroll
    for (int d = 0; d < Dv; ++d) {
        // Row-contiguous 16B reads: ds_read_b128, broadcast/2-way at worst.
        const float4 a4 = *reinterpret_cast<const float4*>(&a_s[d][ty * 4]);
        const float4 b4 = *reinterpret_cast<const float4*>(&b_s[d][tx * 4]);
        const float av[4] = {a4.x, a4.y, a4.z, a4.w};
        const float bw[4] = {b4.x, b4.y, b4.z, b4.w};
        #pragma unroll
        for (int i = 0; i < 4; ++i)
            #pragma unroll
            for (int j = 0; j < 4; ++j)
                acc[i][j] = fmaf(av[i], bw[j], acc[i][j]);
    }

    // ---- store phase: 4 coalesced float4 rows per thread ----
    const float cb = cbias[0];
    float* outb = out + (size_t)b * Nv * Mv;
    #pragma unroll
    for (int i = 0; i < 4; ++i) {
        float4 v;
        v.x = acc[i][0] + cb;
        v.y = acc[i][1] + cb;
        v.z = acc[i][2] + cb;
        v.w = acc[i][3] + cb;
        *reinterpret_cast<float4*>(
            outb + (size_t)(n0 + ty * 4 + i) * Mv + (m0 + tx * 4)) = v;
    }
}

extern "C" void kernel_launch(void* const* d_in, const int* in_sizes, int n_in,
                              void* d_out, int out_size, void* d_ws, size_t ws_size,
                              hipStream_t stream) {
    const float* x1 = (const float*)d_in[0];   // [B,N,D]
    const float* x2 = (const float*)d_in[1];   // [B,M,D]
    const float* cb = (const float*)d_in[2];   // [1]
    float* out = (float*)d_out;                // [B,N,M]

    dim3 grid(Mv / TILE, Nv / TILE, Bv);       // 64 x 64 x 4 blocks
    pairwise_dot_bias_kernel<<<grid, 256, 0, stream>>>(x1, x2, cb, out);
}